// Round 5
// baseline (250.309 us; speedup 1.0000x reference)
//
#include <hip/hip_runtime.h>
#include <hip/hip_bf16.h>
#include <cstdint>

// MxDNA deformable conv block, MI355X/gfx950.
// Round 5: K2 repack (W -> bf16 WB[d][k*256+e]) + single fused kernel:
//   per-token coefficients (quad-shuffle dots, registers only) +
//   gather-lerp A-staging + bf16 MFMA GEMM, BM=128 x BN=256 (full width),
//   512 threads (8 waves, 2M x 4N), double-buffered LDS, prefetch dist 2.

#define N_TOK 8192
#define DIM   256
#define KW    768        // reduction length K*D
#define BM    128
#define BN    256
#define BK    32

typedef unsigned short u16;
typedef __attribute__((ext_vector_type(4))) float    floatx4;
typedef __attribute__((ext_vector_type(8))) __bf16   bf16x8;
typedef __attribute__((ext_vector_type(8))) u16      ushortx8;

__device__ __forceinline__ u16 f32_to_bf16_rne(float f) {
    uint32_t u = __float_as_uint(f);
    u += 0x7fffu + ((u >> 16) & 1u);
    return (u16)(u >> 16);
}

// ---------------- Kernel A: repack weight to bf16 WB[d][k*256+e] ----------------
__global__ __launch_bounds__(256) void packw_kernel(
    const float* __restrict__ W, u16* __restrict__ WB)
{
    const int d = blockIdx.x;
    const int e = threadIdx.x;
#pragma unroll
    for (int k = 0; k < 3; ++k)
        WB[d * KW + k * DIM + e] = f32_to_bf16_rne(W[d * KW + e * 3 + k]);
}

// ---------------- Kernel B: fused coef + gather/lerp + MFMA GEMM ----------------
// 512 thr (8 waves), tile 128(M) x 256(N), BK=32, 24 K-iters.
// LDS rows padded to 40 shorts (80 B): 16-lane b128 reads are 2-way (free).
// Double buffer: iter kk reads buf[kk&1], writes buf[kk&1 ^ 1]; single
// end-of-iter barrier separates both cross-iteration hazards.
__global__ __launch_bounds__(512, 4) void deform_gemm_kernel(
    const float* __restrict__ x, const float* __restrict__ offw,
    const float* __restrict__ modw, const u16* __restrict__ WB,
    float* __restrict__ out)
{
    __shared__ __align__(16) u16 As[2][BM * 40];   // 2 x 10240 B
    __shared__ __align__(16) u16 Bs[2][BN * 40];   // 2 x 20480 B

    const int tid  = threadIdx.x;
    const int wave = tid >> 6;
    const int lane = tid & 63;
    const int t0 = blockIdx.x * BM;
    const float* xb = x + (size_t)(t0 / N_TOK) * N_TOK * DIM;  // batch base (BM | N_TOK)

    const int tq  = tid >> 2;        // token-local 0..127 (A-staging row)
    const int qd  = tid & 3;         // quarter: 8-short (16 B) segment
    const int brow = tid >> 1;       // B-staging row 0..255
    const int bh   = tid & 1;        // B-staging half (16 shorts)
    const int wm = (wave & 1) * 64;  // wave quadrant in M (2)
    const int wn = (wave >> 1) * 64; // wave quadrant in N (4)
    const int lrow = lane & 15;
    const int lq   = lane >> 4;

    // ---- phase 0: per-token coefficients, 4 threads/token, registers only
    int4 cc0, cc1, cc2;
    {
        const int t_abs = t0 + tq;
        const float4* xr = (const float4*)(x + (size_t)t_abs * DIM + qd * 64);
        float s[6] = {0.f, 0.f, 0.f, 0.f, 0.f, 0.f};
#pragma unroll
        for (int j = 0; j < 16; ++j) {
            const float4 xv = xr[j];
#pragma unroll
            for (int k = 0; k < 3; ++k) {
                const float4 wv = ((const float4*)(offw + k * DIM + qd * 64))[j];
                s[k]     += xv.x * wv.x + xv.y * wv.y + xv.z * wv.z + xv.w * wv.w;
                const float4 mv = ((const float4*)(modw + k * DIM + qd * 64))[j];
                s[3 + k] += xv.x * mv.x + xv.y * mv.y + xv.z * mv.z + xv.w * mv.w;
            }
        }
#pragma unroll
        for (int i = 0; i < 6; ++i) {
            s[i] += __shfl_xor(s[i], 1, 64);
            s[i] += __shfl_xor(s[i], 2, 64);
        }
        const int n = t_abs & (N_TOK - 1);
        int4 cc[3];
#pragma unroll
        for (int k = 0; k < 3; ++k) {
            float pos   = (float)(n + k - 1) + s[k];
            bool  valid = (pos >= 0.0f) && (pos < (float)N_TOK);
            float ff = floorf(pos);
            ff = fminf(fmaxf(ff, 0.0f), (float)(N_TOK - 1));
            int   fi = (int)ff;
            int   ci = min(fi + 1, N_TOK - 1);
            float wc = pos - ff;
            float m  = valid ? (1.0f / (1.0f + expf(-s[3 + k]))) : 0.0f;
            cc[k] = make_int4(fi, ci, __float_as_int((1.0f - wc) * m),
                                      __float_as_int(wc * m));
        }
        cc0 = cc[0]; cc1 = cc[1]; cc2 = cc[2];
    }

    // prefetch registers (slice kk's data)
    float4 pf[2], pc[2];   // 8 x-cols from each of 2 rows
    uint4  pb0, pb1;       // 16 B-shorts
    float  wA, wC;

    auto loadg = [&](int kk) {
        const int tap = kk >> 3;
        const int4 c = (tap == 0) ? cc0 : (tap == 1 ? cc1 : cc2);
        const int e0 = (kk & 7) * 32 + qd * 8;
        wA = __int_as_float(c.z);
        wC = __int_as_float(c.w);
        const float4* rowf = (const float4*)(xb + (size_t)c.x * DIM + e0);
        const float4* rowc = (const float4*)(xb + (size_t)c.y * DIM + e0);
        pf[0] = rowf[0]; pf[1] = rowf[1];
        pc[0] = rowc[0]; pc[1] = rowc[1];
        const uint4* g = (const uint4*)(WB + (size_t)brow * KW + kk * BK + bh * 16);
        pb0 = g[0];
        pb1 = g[1];
    };

    auto packstore = [&](int buf) {
        uint32_t p[4];
#pragma unroll
        for (int j = 0; j < 2; ++j) {
            float r0 = wA * pf[j].x + wC * pc[j].x;
            float r1 = wA * pf[j].y + wC * pc[j].y;
            float r2 = wA * pf[j].z + wC * pc[j].z;
            float r3 = wA * pf[j].w + wC * pc[j].w;
            p[j * 2 + 0] = __builtin_amdgcn_perm(__float_as_uint(r1), __float_as_uint(r0), 0x07060302u);
            p[j * 2 + 1] = __builtin_amdgcn_perm(__float_as_uint(r3), __float_as_uint(r2), 0x07060302u);
        }
        *(uint4*)&As[buf][tq * 40 + qd * 8] = make_uint4(p[0], p[1], p[2], p[3]);
        uint4* bdst = (uint4*)&Bs[buf][brow * 40 + bh * 16];
        bdst[0] = pb0;
        bdst[1] = pb1;
    };

    // prologue: slice 0 -> buf0; prefetch slice 1 into registers
    loadg(0);
    packstore(0);
    loadg(1);

    floatx4 acc[4][4];
#pragma unroll
    for (int i = 0; i < 4; ++i)
#pragma unroll
        for (int j = 0; j < 4; ++j) acc[i][j] = (floatx4){0.f, 0.f, 0.f, 0.f};

    __syncthreads();                 // buf0 visible

    for (int kk = 0; kk < 24; ++kk) {
        const int cur = kk & 1;
        bf16x8 af[4], bfv[4];
#pragma unroll
        for (int i = 0; i < 4; ++i)
            af[i] = __builtin_bit_cast(bf16x8, *(const ushortx8*)&As[cur][(wm + i * 16 + lrow) * 40 + lq * 8]);
#pragma unroll
        for (int j = 0; j < 4; ++j)
            bfv[j] = __builtin_bit_cast(bf16x8, *(const ushortx8*)&Bs[cur][(wn + j * 16 + lrow) * 40 + lq * 8]);
        if (kk < 23) packstore(cur ^ 1);   // stage slice kk+1 into other buffer
        if (kk < 22) loadg(kk + 2);        // refill prefetch with slice kk+2
#pragma unroll
        for (int i = 0; i < 4; ++i)
#pragma unroll
            for (int j = 0; j < 4; ++j)
                acc[i][j] = __builtin_amdgcn_mfma_f32_16x16x32_bf16(af[i], bfv[j], acc[i][j], 0, 0, 0);
        __syncthreads();             // separates writes(kk)<->reads(kk+1) both ways
    }

    // ---- epilogue: C/D layout col = lane&15, row = (lane>>4)*4 + reg
#pragma unroll
    for (int i = 0; i < 4; ++i) {
#pragma unroll
        for (int r = 0; r < 4; ++r) {
            const int token = t0 + wm + i * 16 + lq * 4 + r;
            float* op = out + (size_t)token * DIM + wn + lrow;
#pragma unroll
            for (int j = 0; j < 4; ++j) op[j * 16] = acc[i][j][r];
        }
    }
}

extern "C" void kernel_launch(void* const* d_in, const int* in_sizes, int n_in,
                              void* d_out, int out_size, void* d_ws, size_t ws_size,
                              hipStream_t stream)
{
    const float* x    = (const float*)d_in[0];  // (8, 8192, 256)
    const float* offw = (const float*)d_in[1];  // (3, 256)
    const float* modw = (const float*)d_in[2];  // (3, 256)
    const float* W    = (const float*)d_in[3];  // (256, 256, 3)
    float* out = (float*)d_out;                 // (8, 8192, 256)

    u16* WB = (u16*)d_ws;                       // 393,216 B

    packw_kernel<<<DIM, 256, 0, stream>>>(W, WB);
    const int tot_tok = 8 * N_TOK;              // 65536
    deform_gemm_kernel<<<tot_tok / BM, 512, 0, stream>>>(x, offw, modw, WB, out);
}

// Round 6
// 228.699 us; speedup vs baseline: 1.0945x; 1.0945x over previous
//
#include <hip/hip_runtime.h>
#include <hip/hip_bf16.h>
#include <cstdint>

// MxDNA deformable conv block, MI355X/gfx950.
// Round 6: round-4 proven core (256 thr, BM=128 x BN=128, dbuf LDS, 1 barrier/iter,
// register prefetch dist 2) + fused coef prologue (no separate K1, no coef ws) +
// slice-major K order (L1 reuse of gather rows) + XCD-pair swizzle (ntile pair
// shares an XCD L2 -> x fetched once).

#define N_TOK 8192
#define DIM   256
#define KW    768        // reduction length K*D
#define BM    128
#define BN    128
#define BK    32

typedef unsigned short u16;
typedef __attribute__((ext_vector_type(4))) float    floatx4;
typedef __attribute__((ext_vector_type(8))) __bf16   bf16x8;
typedef __attribute__((ext_vector_type(8))) u16      ushortx8;

__device__ __forceinline__ u16 f32_to_bf16_rne(float f) {
    uint32_t u = __float_as_uint(f);
    u += 0x7fffu + ((u >> 16) & 1u);
    return (u16)(u >> 16);
}

// ---------------- Kernel A: repack weight to bf16 WB[d][k*256+e] ----------------
__global__ __launch_bounds__(256) void packw_kernel(
    const float* __restrict__ W, u16* __restrict__ WB)
{
    const int d = blockIdx.x;
    const int e = threadIdx.x;
#pragma unroll
    for (int k = 0; k < 3; ++k)
        WB[d * KW + k * DIM + e] = f32_to_bf16_rne(W[d * KW + e * 3 + k]);
}

// ---------------- Kernel B: fused coef + gather/lerp + MFMA GEMM ----------------
// 256 thr (4 waves), tile 128(M) x 128(N), BK=32, 24 K-iters (slice-major).
// LDS rows padded to 40 shorts (80 B). Double buffer: iter kk reads buf[kk&1],
// writes buf[kk&1 ^ 1]; single end-of-iter barrier covers both hazards.
__global__ __launch_bounds__(256) void deform_gemm_kernel(
    const float* __restrict__ x, const float* __restrict__ offw,
    const float* __restrict__ modw, const u16* __restrict__ WB,
    float* __restrict__ out)
{
    __shared__ __align__(16) u16 As[2][BM * 40];   // 2 x 10240 B
    __shared__ __align__(16) u16 Bs[2][BN * 40];   // 2 x 10240 B

    const int tid  = threadIdx.x;
    const int wave = tid >> 6;
    const int lane = tid & 63;

    // XCD-pair swizzle: blocks g and g+8 share (mtile, XCD) and split ntile,
    // so both halves' identical x-row demand is served by one XCD L2.
    const int g  = blockIdx.x;
    const int mtile = (g >> 4) * 8 + (g & 7);
    const int ntile = (g >> 3) & 1;
    const int t0 = mtile * BM;
    const int n0 = ntile * BN;
    const float* xb = x + (size_t)(t0 / N_TOK) * N_TOK * DIM;  // batch base (BM | N_TOK)

    const int tl = tid >> 1;         // token-local 0..127
    const int eh = tid & 1;          // 16-column half
    const int wm = (wave & 1) * 64;  // wave quadrant in M
    const int wn = (wave >> 1) * 64; // wave quadrant in N
    const int lrow = lane & 15;
    const int lq   = lane >> 4;

    // ---- phase 0: per-token tap coefficients, 2 threads/token, registers only
    int4 cc0, cc1, cc2;
    {
        const int t_abs = t0 + tl;
        const float4* xr = (const float4*)(x + (size_t)t_abs * DIM + eh * 128);
        float s[6] = {0.f, 0.f, 0.f, 0.f, 0.f, 0.f};
#pragma unroll
        for (int j = 0; j < 32; ++j) {
            const float4 xv = xr[j];
#pragma unroll
            for (int k = 0; k < 3; ++k) {
                const float4 wv = ((const float4*)(offw + k * DIM + eh * 128))[j];
                s[k]     += xv.x * wv.x + xv.y * wv.y + xv.z * wv.z + xv.w * wv.w;
                const float4 mv = ((const float4*)(modw + k * DIM + eh * 128))[j];
                s[3 + k] += xv.x * mv.x + xv.y * mv.y + xv.z * mv.z + xv.w * mv.w;
            }
        }
#pragma unroll
        for (int i = 0; i < 6; ++i) s[i] += __shfl_xor(s[i], 1, 64);  // pair lanes share a token
        const int n = t_abs & (N_TOK - 1);
        int4 cc[3];
#pragma unroll
        for (int k = 0; k < 3; ++k) {
            float pos   = (float)(n + k - 1) + s[k];
            bool  valid = (pos >= 0.0f) && (pos < (float)N_TOK);
            float ff = floorf(pos);
            ff = fminf(fmaxf(ff, 0.0f), (float)(N_TOK - 1));
            int   fi = (int)ff;
            int   ci = min(fi + 1, N_TOK - 1);
            float wc = pos - ff;
            float m  = valid ? (1.0f / (1.0f + expf(-s[3 + k]))) : 0.0f;
            cc[k] = make_int4(fi, ci, __float_as_int((1.0f - wc) * m),
                                      __float_as_int(wc * m));
        }
        cc0 = cc[0]; cc1 = cc[1]; cc2 = cc[2];
    }

    // prefetch registers (slice kk's data)
    float4 pf[4], pc[4];
    uint4  pb0, pb1;
    float  wA, wC;

    // slice-major order: kk = s*3 + tap; x cols = s*32, WB col = tap*256 + s*32.
    auto loadg = [&](int kk) {
        const int sidx = kk / 3;
        const int tap  = kk - sidx * 3;
        const int4 c = (tap == 0) ? cc0 : (tap == 1 ? cc1 : cc2);
        const int xcol = sidx * 32 + eh * 16;
        wA = __int_as_float(c.z);
        wC = __int_as_float(c.w);
        const float4* rowf = (const float4*)(xb + (size_t)c.x * DIM + xcol);
        const float4* rowc = (const float4*)(xb + (size_t)c.y * DIM + xcol);
#pragma unroll
        for (int j = 0; j < 4; ++j) { pf[j] = rowf[j]; pc[j] = rowc[j]; }
        const uint4* gp = (const uint4*)(WB + (size_t)(n0 + tl) * KW + tap * DIM + xcol);
        pb0 = gp[0];
        pb1 = gp[1];
    };

    auto packstore = [&](int buf) {
        uint32_t p[8];
#pragma unroll
        for (int j = 0; j < 4; ++j) {
            float r0 = wA * pf[j].x + wC * pc[j].x;
            float r1 = wA * pf[j].y + wC * pc[j].y;
            float r2 = wA * pf[j].z + wC * pc[j].z;
            float r3 = wA * pf[j].w + wC * pc[j].w;
            p[j * 2 + 0] = __builtin_amdgcn_perm(__float_as_uint(r1), __float_as_uint(r0), 0x07060302u);
            p[j * 2 + 1] = __builtin_amdgcn_perm(__float_as_uint(r3), __float_as_uint(r2), 0x07060302u);
        }
        uint4* adst = (uint4*)&As[buf][tl * 40 + eh * 16];
        adst[0] = make_uint4(p[0], p[1], p[2], p[3]);
        adst[1] = make_uint4(p[4], p[5], p[6], p[7]);
        uint4* bdst = (uint4*)&Bs[buf][tl * 40 + eh * 16];
        bdst[0] = pb0;
        bdst[1] = pb1;
    };

    // prologue: slice 0 -> buf0; prefetch slice 1 into registers
    loadg(0);
    packstore(0);
    loadg(1);

    floatx4 acc[4][4];
#pragma unroll
    for (int i = 0; i < 4; ++i)
#pragma unroll
        for (int j = 0; j < 4; ++j) acc[i][j] = (floatx4){0.f, 0.f, 0.f, 0.f};

    __syncthreads();                 // buf0 visible

    for (int kk = 0; kk < 24; ++kk) {
        const int cur = kk & 1;
        bf16x8 af[4], bfv[4];
#pragma unroll
        for (int i = 0; i < 4; ++i)
            af[i] = __builtin_bit_cast(bf16x8, *(const ushortx8*)&As[cur][(wm + i * 16 + lrow) * 40 + lq * 8]);
#pragma unroll
        for (int j = 0; j < 4; ++j)
            bfv[j] = __builtin_bit_cast(bf16x8, *(const ushortx8*)&Bs[cur][(wn + j * 16 + lrow) * 40 + lq * 8]);
        if (kk < 23) packstore(cur ^ 1);   // stage slice kk+1 into other buffer
        if (kk < 22) loadg(kk + 2);        // refill prefetch with slice kk+2
#pragma unroll
        for (int i = 0; i < 4; ++i)
#pragma unroll
            for (int j = 0; j < 4; ++j)
                acc[i][j] = __builtin_amdgcn_mfma_f32_16x16x32_bf16(af[i], bfv[j], acc[i][j], 0, 0, 0);
        __syncthreads();             // separates writes(kk)<->reads(kk+1) both ways
    }

    // ---- epilogue: C/D layout col = lane&15, row = (lane>>4)*4 + reg
#pragma unroll
    for (int i = 0; i < 4; ++i) {
#pragma unroll
        for (int r = 0; r < 4; ++r) {
            const int token = t0 + wm + i * 16 + lq * 4 + r;
            float* op = out + (size_t)token * DIM + n0 + wn + lrow;
#pragma unroll
            for (int j = 0; j < 4; ++j) op[j * 16] = acc[i][j][r];
        }
    }
}

extern "C" void kernel_launch(void* const* d_in, const int* in_sizes, int n_in,
                              void* d_out, int out_size, void* d_ws, size_t ws_size,
                              hipStream_t stream)
{
    const float* x    = (const float*)d_in[0];  // (8, 8192, 256)
    const float* offw = (const float*)d_in[1];  // (3, 256)
    const float* modw = (const float*)d_in[2];  // (3, 256)
    const float* W    = (const float*)d_in[3];  // (256, 256, 3)
    float* out = (float*)d_out;                 // (8, 8192, 256)

    u16* WB = (u16*)d_ws;                       // 393,216 B

    packw_kernel<<<DIM, 256, 0, stream>>>(W, WB);
    const int tot_tok = 8 * N_TOK;              // 65536
    deform_gemm_kernel<<<(tot_tok / BM) * 2, 256, 0, stream>>>(x, offw, modw, WB, out);
}

// Round 7
// 211.126 us; speedup vs baseline: 1.1856x; 1.0832x over previous
//
#include <hip/hip_runtime.h>
#include <hip/hip_bf16.h>
#include <cstdint>

// MxDNA deformable conv block, MI355X/gfx950.
// Round 7 = round-4 proven core (separate coef kernel, tap-major K order,
// 256 thr, BM=128 x BN=128, dbuf A-LDS, 1 barrier/iter, A prefetch dist 2)
//   + XCD-pair swizzle (verified: FETCH 203 MB -> 69 MB in round 6)
//   + B operand LDS path removed: B fragments load global->register straight
//     from L2-resident WB (384 KB), 1-iter register prefetch.

#define N_TOK 8192
#define DIM   256
#define KW    768        // reduction length K*D
#define BM    128
#define BN    128
#define BK    32

typedef unsigned short u16;
typedef __attribute__((ext_vector_type(4))) float    floatx4;
typedef __attribute__((ext_vector_type(8))) __bf16   bf16x8;
typedef __attribute__((ext_vector_type(8))) u16      ushortx8;

__device__ __forceinline__ u16 f32_to_bf16_rne(float f) {
    uint32_t u = __float_as_uint(f);
    u += 0x7fffu + ((u >> 16) & 1u);
    return (u16)(u >> 16);
}

// ---------------- Kernel 1: per-token coefficients (round-2 proven) ----------------
__global__ __launch_bounds__(256) void coef_kernel(
    const float* __restrict__ x, const float* __restrict__ offw,
    const float* __restrict__ modw, int4* __restrict__ coef)
{
    const int wave = threadIdx.x >> 6;
    const int lane = threadIdx.x & 63;
    const int t = blockIdx.x * 4 + wave;

    const float4 xv = ((const float4*)(x + (size_t)t * DIM))[lane];
    float s[6];
#pragma unroll
    for (int k = 0; k < 3; ++k) {
        float4 wv = ((const float4*)(offw + k * DIM))[lane];
        s[k]     = xv.x * wv.x + xv.y * wv.y + xv.z * wv.z + xv.w * wv.w;
        float4 mv = ((const float4*)(modw + k * DIM))[lane];
        s[3 + k] = xv.x * mv.x + xv.y * mv.y + xv.z * mv.z + xv.w * mv.w;
    }
#pragma unroll
    for (int d = 1; d < 64; d <<= 1) {
#pragma unroll
        for (int i = 0; i < 6; ++i) s[i] += __shfl_xor(s[i], d, 64);
    }
    if (lane < 3) {
        const int k = lane;
        const int n = t & (N_TOK - 1);
        float pos   = (float)(n + k - 1) + s[k];
        bool  valid = (pos >= 0.0f) && (pos < (float)N_TOK);
        float ff = floorf(pos);
        ff = fminf(fmaxf(ff, 0.0f), (float)(N_TOK - 1));
        int   fi = (int)ff;
        int   ci = min(fi + 1, N_TOK - 1);
        float wc = pos - ff;
        float m  = valid ? (1.0f / (1.0f + expf(-s[3 + k]))) : 0.0f;
        coef[t * 3 + k] = make_int4(fi, ci,
                                    __float_as_int((1.0f - wc) * m),
                                    __float_as_int(wc * m));
    }
}

// ---------------- Kernel 2: repack weight to bf16 WB[d][k*256+e] ----------------
__global__ __launch_bounds__(256) void packw_kernel(
    const float* __restrict__ W, u16* __restrict__ WB)
{
    const int d = blockIdx.x;
    const int e = threadIdx.x;
#pragma unroll
    for (int k = 0; k < 3; ++k)
        WB[d * KW + k * DIM + e] = f32_to_bf16_rne(W[d * KW + e * 3 + k]);
}

// ---------------- Kernel 3: gather/lerp + MFMA GEMM ----------------
// 256 thr (4 waves), tile 128(M) x 128(N), BK=32, 24 K-iters tap-major.
// A staged via double-buffered LDS (rows padded to 40 shorts); B fragments
// loaded global->register from L2-resident WB with 1-iter prefetch.
__global__ __launch_bounds__(256) void deform_gemm_kernel(
    const float* __restrict__ x, const u16* __restrict__ WB,
    const int4* __restrict__ coef, float* __restrict__ out)
{
    __shared__ __align__(16) u16 As[2][BM * 40];   // 2 x 10240 B

    const int tid  = threadIdx.x;
    const int wave = tid >> 6;
    const int lane = tid & 63;

    // XCD-pair swizzle: blocks g and g+8 share mtile (and XCD under round-robin
    // g%8 placement) and split ntile -> x gather served once per XCD L2.
    const int g  = blockIdx.x;
    const int mtile = (g >> 4) * 8 + (g & 7);
    const int ntile = (g >> 3) & 1;
    const int t0 = mtile * BM;
    const int n0 = ntile * BN;
    const float* xb = x + (size_t)(t0 / N_TOK) * N_TOK * DIM;  // batch base (BM | N_TOK)

    const int tl = tid >> 1;         // token-local 0..127
    const int eh = tid & 1;          // 16-column half
    const int wm = (wave & 1) * 64;  // wave quadrant in M
    const int wn = (wave >> 1) * 64; // wave quadrant in N
    const int lrow = lane & 15;
    const int lq   = lane >> 4;

    // per-thread coefficients for token t0+tl (3 taps) — registers
    const int4 cc0 = coef[(size_t)(t0 + tl) * 3 + 0];
    const int4 cc1 = coef[(size_t)(t0 + tl) * 3 + 1];
    const int4 cc2 = coef[(size_t)(t0 + tl) * 3 + 2];

    // A prefetch registers (slice kk)
    float4 pf[4], pc[4];
    float  wA, wC;

    auto loadA = [&](int kk) {                    // tap-major: tap = kk>>3
        const int tap = kk >> 3;
        const int4 c = (tap == 0) ? cc0 : (tap == 1 ? cc1 : cc2);
        const int e0 = (kk & 7) * 32 + eh * 16;
        wA = __int_as_float(c.z);
        wC = __int_as_float(c.w);
        const float4* rowf = (const float4*)(xb + (size_t)c.x * DIM + e0);
        const float4* rowc = (const float4*)(xb + (size_t)c.y * DIM + e0);
#pragma unroll
        for (int j = 0; j < 4; ++j) { pf[j] = rowf[j]; pc[j] = rowc[j]; }
    };

    auto packstoreA = [&](int buf) {
        uint32_t p[8];
#pragma unroll
        for (int j = 0; j < 4; ++j) {
            float r0 = wA * pf[j].x + wC * pc[j].x;
            float r1 = wA * pf[j].y + wC * pc[j].y;
            float r2 = wA * pf[j].z + wC * pc[j].z;
            float r3 = wA * pf[j].w + wC * pc[j].w;
            p[j * 2 + 0] = __builtin_amdgcn_perm(__float_as_uint(r1), __float_as_uint(r0), 0x07060302u);
            p[j * 2 + 1] = __builtin_amdgcn_perm(__float_as_uint(r3), __float_as_uint(r2), 0x07060302u);
        }
        uint4* adst = (uint4*)&As[buf][tl * 40 + eh * 16];
        adst[0] = make_uint4(p[0], p[1], p[2], p[3]);
        adst[1] = make_uint4(p[4], p[5], p[6], p[7]);
    };

    // B fragment loads: B[n=lrow][k=lq*8+j] for each 16-wide n-subtile
    uint4 bq[4];
    auto loadB = [&](int kk) {
#pragma unroll
        for (int j = 0; j < 4; ++j)
            bq[j] = *(const uint4*)(WB + (size_t)(n0 + wn + j * 16 + lrow) * KW + kk * BK + lq * 8);
    };

    // prologue: slice 0 -> buf0; prefetch A slice 1; prefetch B slice 0
    loadA(0);
    packstoreA(0);
    loadA(1);
    loadB(0);

    floatx4 acc[4][4];
#pragma unroll
    for (int i = 0; i < 4; ++i)
#pragma unroll
        for (int j = 0; j < 4; ++j) acc[i][j] = (floatx4){0.f, 0.f, 0.f, 0.f};

    __syncthreads();                 // buf0 visible

    for (int kk = 0; kk < 24; ++kk) {
        const int cur = kk & 1;
        bf16x8 af[4];
#pragma unroll
        for (int i = 0; i < 4; ++i)
            af[i] = __builtin_bit_cast(bf16x8, *(const ushortx8*)&As[cur][(wm + i * 16 + lrow) * 40 + lq * 8]);
        uint4 bc[4];
#pragma unroll
        for (int j = 0; j < 4; ++j) bc[j] = bq[j];
        if (kk < 23) loadB(kk + 1);        // prefetch B slice kk+1 (L2)
        if (kk < 23) packstoreA(cur ^ 1);  // stage A slice kk+1 into other buffer
        if (kk < 22) loadA(kk + 2);        // refill A prefetch with slice kk+2
#pragma unroll
        for (int i = 0; i < 4; ++i)
#pragma unroll
            for (int j = 0; j < 4; ++j)
                acc[i][j] = __builtin_amdgcn_mfma_f32_16x16x32_bf16(
                    af[i], __builtin_bit_cast(bf16x8, bc[j]), acc[i][j], 0, 0, 0);
        __syncthreads();             // As dbuf hazard separation (both directions)
    }

    // ---- epilogue: C/D layout col = lane&15, row = (lane>>4)*4 + reg
#pragma unroll
    for (int i = 0; i < 4; ++i) {
#pragma unroll
        for (int r = 0; r < 4; ++r) {
            const int token = t0 + wm + i * 16 + lq * 4 + r;
            float* op = out + (size_t)token * DIM + n0 + wn + lrow;
#pragma unroll
            for (int j = 0; j < 4; ++j) op[j * 16] = acc[i][j][r];
        }
    }
}

extern "C" void kernel_launch(void* const* d_in, const int* in_sizes, int n_in,
                              void* d_out, int out_size, void* d_ws, size_t ws_size,
                              hipStream_t stream)
{
    const float* x    = (const float*)d_in[0];  // (8, 8192, 256)
    const float* offw = (const float*)d_in[1];  // (3, 256)
    const float* modw = (const float*)d_in[2];  // (3, 256)
    const float* W    = (const float*)d_in[3];  // (256, 256, 3)
    float* out = (float*)d_out;                 // (8, 8192, 256)

    const int tot_tok = 8 * N_TOK;              // 65536
    int4* coef = (int4*)d_ws;                                       // 3,145,728 B
    u16*  WB   = (u16*)((char*)d_ws + (size_t)tot_tok * 3 * 16);    //   393,216 B

    coef_kernel<<<tot_tok / 4, 256, 0, stream>>>(x, offw, modw, coef);
    packw_kernel<<<DIM, 256, 0, stream>>>(W, WB);
    deform_gemm_kernel<<<(tot_tok / BM) * 2, 256, 0, stream>>>(x, WB, coef, out);
}